// Round 4
// baseline (150.121 us; speedup 1.0000x reference)
//
#include <hip/hip_runtime.h>
#include <hip/hip_bf16.h>

// CARAFE: B=4, C=128, H=W=64, C_MID=64, S=2, K=5
#define HW    4096
#define C_IN  128
#define C_MID 64

typedef __attribute__((ext_vector_type(8))) short  short8;   // 8 bf16 (4 VGPRs)
typedef __attribute__((ext_vector_type(4))) float  floatx4;  // MFMA C/D

// workspace layout (BYTE offsets)
#define OFF_W1T 0ul        // float[128*64]            = 32768 B
#define OFF_W2B 32768ul    // bf16 [112*576]           = 129024 B
#define OFF_H   161792ul   // bf16 [4*4096*64]         = 2097152 B
#define OFF_KER 2258944ul  // float[4*64*100*64]       = 6553600 B  (end ~8.8 MB)

// ---------------- prep: w1 transpose (fp32) + w2 -> bf16 [n][k] with k = tap*64 + c ----------
__global__ __launch_bounds__(256) void prep_kernel(const float* __restrict__ w1,
                                                   const float* __restrict__ w2,
                                                   char* __restrict__ ws) {
    int tid = blockIdx.x * 256 + threadIdx.x;
    if (tid < 8192) {
        int o = tid & 63, c = tid >> 6;
        ((float*)(ws + OFF_W1T))[c * 64 + o] = w1[o * 128 + c];
    } else if (tid < 8192 + 112 * 576) {
        int i = tid - 8192;
        int n = i / 576;          // 0..111 (100..111 zero pad)
        int k = i - n * 576;      // k = t*64 + c
        int t = k >> 6, c = k & 63;
        float v = (n < 100) ? w2[(n * 64 + c) * 9 + t] : 0.f;
        ((__hip_bfloat16*)(ws + OFF_W2B))[i] = __float2bfloat16(v);
    }
}

// ---------------- k1: 1x1 conv + BN + ReLU -> h bf16 [b][pix][c] ----------------
__global__ __launch_bounds__(256) void k1_pointwise(const float* __restrict__ x,
                                                    char* __restrict__ ws,
                                                    const float* __restrict__ gamma,
                                                    const float* __restrict__ beta,
                                                    const float* __restrict__ mean,
                                                    const float* __restrict__ var) {
    __shared__ float xs[128 * 64];   // [c][i], 32 KB
    int b   = blockIdx.x >> 6;
    int pp0 = (blockIdx.x & 63) * 64;

    const float* xb = x + (size_t)b * C_IN * HW + pp0;
    for (int idx = threadIdx.x; idx < 8192; idx += 256) {
        int c = idx >> 6, i = idx & 63;
        xs[idx] = xb[(size_t)c * HW + i];
    }
    __syncthreads();

    int wave = threadIdx.x >> 6, pix = threadIdx.x & 63;
    int o0 = wave * 16;
    const float* w1t = (const float*)(ws + OFF_W1T);

    float acc[16];
    #pragma unroll
    for (int j = 0; j < 16; ++j) acc[j] = 0.f;

    for (int c = 0; c < C_IN; ++c) {
        float xv = xs[c * 64 + pix];
        const float* wr = w1t + c * 64 + o0;   // wave-uniform -> s_load
        #pragma unroll
        for (int j = 0; j < 16; ++j) acc[j] = fmaf(wr[j], xv, acc[j]);
    }

    union { uint4 v; __hip_bfloat16 h[8]; } u0, u1;
    #pragma unroll
    for (int j = 0; j < 16; ++j) {
        int o = o0 + j;
        float inv = gamma[o] * rsqrtf(var[o] + 1e-5f);
        float add = beta[o] - mean[o] * inv;
        float v = fmaxf(fmaf(acc[j], inv, add), 0.f);
        if (j < 8) u0.h[j] = __float2bfloat16(v); else u1.h[j - 8] = __float2bfloat16(v);
    }
    __hip_bfloat16* hout = (__hip_bfloat16*)(ws + OFF_H) + ((size_t)(b * 4096 + pp0 + pix)) * 64 + o0;
    *(uint4*)(hout)     = u0.v;
    *(uint4*)(hout + 8) = u1.v;
}

// ---------------- k2: 3x3 conv (64->100) as bf16 MFMA GEMM + fused softmax ----------------
// grid 512 = b(4) x tile8(64) x half(2); block = 8x4 pixel tile, 4 waves:
// wave = (psub: 16 pixels, nh: N-half). nh=0 -> n 0..63 (4 tiles), nh=1 -> n 64..111 (3 tiles)
template<int FC>
__device__ __forceinline__ void k2_gemm_body(const __hip_bfloat16* __restrict__ bp,
                                             const __hip_bfloat16* __restrict__ hs,
                                             int py, int px, int q, floatx4* acc) {
    short8 bcur[FC];
    #pragma unroll
    for (int f = 0; f < FC; ++f) bcur[f] = *(const short8*)(bp + f * 9216);
    for (int s = 0; s < 18; ++s) {
        int t = s >> 1, c0 = (s & 1) * 32;
        short8 a = *(const short8*)(&hs[((py + t / 3) * 10 + (px + t % 3)) * 88 + c0 + q * 8]);
        short8 bnx[FC];
        if (s < 17) {
            int ko = (s + 1) * 32;
            #pragma unroll
            for (int f = 0; f < FC; ++f) bnx[f] = *(const short8*)(bp + f * 9216 + ko);
        }
        #pragma unroll
        for (int f = 0; f < FC; ++f)
            acc[f] = __builtin_amdgcn_mfma_f32_16x16x32_bf16(a, bcur[f], acc[f], 0, 0, 0);
        if (s < 17) {
            #pragma unroll
            for (int f = 0; f < FC; ++f) bcur[f] = bnx[f];
        }
    }
}

__global__ __launch_bounds__(256) void k2_conv_softmax(char* __restrict__ ws) {
    __shared__ __hip_bfloat16 hs[60 * 88];   // 6x10 halo rows x 64 ch, stride 88 (10.6 KB)
    __shared__ float lg[32 * 114];           // logits [pix32][n], stride 114 (14.6 KB)

    int b     = blockIdx.x >> 7;
    int r7    = blockIdx.x & 127;
    int tile8 = r7 >> 1;
    int half  = r7 & 1;
    int ty0 = (tile8 >> 3) * 8 + half * 4;
    int tx0 = (tile8 & 7) * 8;

    // ---- stage h halo (6x10 pixels x 64 c, bf16) ----
    const __hip_bfloat16* hglob = (const __hip_bfloat16*)(ws + OFF_H) + (size_t)b * 4096 * 64;
    #pragma unroll
    for (int pass = 0; pass < 2; ++pass) {
        int idx = pass * 256 + threadIdx.x;
        if (idx < 480) {
            int r = idx >> 3;                 // halo row 0..59
            int hy = r / 10, hx = r - hy * 10;
            int gy = ty0 + hy - 1, gx = tx0 + hx - 1;
            int ch = (idx & 7) * 8;
            uint4 v = make_uint4(0u, 0u, 0u, 0u);
            if ((unsigned)gy < 64u && (unsigned)gx < 64u)
                v = *(const uint4*)(hglob + (size_t)(gy * 64 + gx) * 64 + ch);
            *(uint4*)(&hs[r * 88 + ch]) = v;
        }
    }
    __syncthreads();

    int lane = threadIdx.x & 63, wave = threadIdx.x >> 6;
    int psub = wave & 1, nh = wave >> 1;
    int q = lane >> 4, m = lane & 15;
    int pixidx = psub * 16 + m;              // local pixel 0..31
    int py = pixidx >> 3, px = pixidx & 7;   // py 0..3, px 0..7

    const __hip_bfloat16* w2b = (const __hip_bfloat16*)(ws + OFF_W2B);
    const __hip_bfloat16* bp  = w2b + (size_t)(nh * 64 + m) * 576 + q * 8;

    floatx4 acc[4];
    #pragma unroll
    for (int f = 0; f < 4; ++f)
        #pragma unroll
        for (int r = 0; r < 4; ++r) acc[f][r] = 0.f;

    if (nh == 0) k2_gemm_body<4>(bp, hs, py, px, q, acc);
    else         k2_gemm_body<3>(bp, hs, py, px, q, acc);

    // ---- dump logits: C/D layout col=lane&15 (n within tile), row=q*4+r (pixel) ----
    int fc = 4 - nh;
    for (int f = 0; f < fc; ++f)
        #pragma unroll
        for (int r = 0; r < 4; ++r)
            lg[(psub * 16 + q * 4 + r) * 114 + nh * 64 + f * 16 + m] = acc[f][r];
    __syncthreads();

    // ---- softmax: 128 (pixel, group) pairs on threads 0..127 ----
    if (threadIdx.x < 128) {
        int pix = threadIdx.x & 31;
        int g   = threadIdx.x >> 5;
        float v[25];
        #pragma unroll
        for (int wi = 0; wi < 25; ++wi) v[wi] = lg[pix * 114 + g * 25 + wi];
        float mx = v[0];
        #pragma unroll
        for (int wi = 1; wi < 25; ++wi) mx = fmaxf(mx, v[wi]);
        float ssum = 0.f;
        #pragma unroll
        for (int wi = 0; wi < 25; ++wi) { v[wi] = __expf(v[wi] - mx); ssum += v[wi]; }
        float rs = 1.f / ssum;

        // ker[(b*64+tile8)][q=t*4+g][pix64], pix64 = half*32 + pixlocal
        float* kbase = (float*)(ws + OFF_KER) + (size_t)(b * 64 + tile8) * 6400 + half * 32 + pix;
        #pragma unroll
        for (int t25 = 0; t25 < 25; ++t25)
            kbase[(t25 * 4 + g) * 64] = v[t25] * rs;
    }
}

// ---------------- k3: 5x5 reassembly + pixel shuffle, x staged in LDS ----------------
__global__ __launch_bounds__(256) void k3_reassemble(const float* __restrict__ x,
                                                     const char* __restrict__ ws,
                                                     float* __restrict__ out) {
    __shared__ float ks[6400];        // [q=t*4+g][pix]
    __shared__ float xs[32 * 144];    // [c][p], p = hy*12+hx (12x12 halo, zero-padded)

    int b    = blockIdx.x >> 6;
    int tile = blockIdx.x & 63;
    int ty0 = (tile >> 3) << 3;
    int tx0 = (tile & 7) << 3;
    int ch0 = blockIdx.y * 32;

    const float* kbase = (const float*)(ws + OFF_KER) + (size_t)blockIdx.x * 6400;
    for (int idx = threadIdx.x; idx < 6400; idx += 256) ks[idx] = kbase[idx];

    const float* xb = x + ((size_t)b * C_IN + ch0) * HW;
    for (int idx = threadIdx.x; idx < 4608; idx += 256) {
        int c = idx / 144;
        int p = idx - c * 144;
        int hy = p / 12, hx = p - hy * 12;
        int gy = ty0 + hy - 2, gx = tx0 + hx - 2;
        float v = 0.f;
        if ((unsigned)gy < 64u && (unsigned)gx < 64u)
            v = xb[(size_t)c * HW + gy * 64 + gx];
        xs[idx] = v;
    }
    __syncthreads();

    int wave = threadIdx.x >> 6;
    int pix  = threadIdx.x & 63;
    int py = pix >> 3, px = pix & 7;
    int Y = ty0 + py, X = tx0 + px;

    float acc[32];  // [8 ch][4 g]
    #pragma unroll
    for (int i = 0; i < 32; ++i) acc[i] = 0.f;

    const float* xw = xs + wave * 8 * 144 + py * 12 + px;
    #pragma unroll 5
    for (int t = 0; t < 25; ++t) {
        int ti = t / 5, tj = t % 5;
        int po = ti * 12 + tj;
        float k0 = ks[(t * 4 + 0) * 64 + pix];
        float k1 = ks[(t * 4 + 1) * 64 + pix];
        float k2 = ks[(t * 4 + 2) * 64 + pix];
        float k3 = ks[(t * 4 + 3) * 64 + pix];
        #pragma unroll
        for (int i = 0; i < 8; ++i) {
            float xv = xw[i * 144 + po];
            acc[i * 4 + 0] = fmaf(xv, k0, acc[i * 4 + 0]);
            acc[i * 4 + 1] = fmaf(xv, k1, acc[i * 4 + 1]);
            acc[i * 4 + 2] = fmaf(xv, k2, acc[i * 4 + 2]);
            acc[i * 4 + 3] = fmaf(xv, k3, acc[i * 4 + 3]);
        }
    }

    int ch = ch0 + wave * 8;
    #pragma unroll
    for (int i = 0; i < 8; ++i) {
        size_t o0 = (((size_t)b * C_IN + ch + i) * 128 + 2 * Y) * 128 + 2 * X;
        *(float2*)(out + o0)       = make_float2(acc[i * 4 + 0], acc[i * 4 + 1]);
        *(float2*)(out + o0 + 128) = make_float2(acc[i * 4 + 2], acc[i * 4 + 3]);
    }
}

extern "C" void kernel_launch(void* const* d_in, const int* in_sizes, int n_in,
                              void* d_out, int out_size, void* d_ws, size_t ws_size,
                              hipStream_t stream) {
    const float* x     = (const float*)d_in[0];
    const float* w1    = (const float*)d_in[1];
    const float* w2    = (const float*)d_in[2];
    const float* gamma = (const float*)d_in[3];
    const float* beta  = (const float*)d_in[4];
    const float* mean  = (const float*)d_in[5];
    const float* var   = (const float*)d_in[6];
    float* out = (float*)d_out;
    char*  ws  = (char*)d_ws;

    prep_kernel<<<284, 256, 0, stream>>>(w1, w2, ws);
    k1_pointwise<<<256, 256, 0, stream>>>(x, ws, gamma, beta, mean, var);
    k2_conv_softmax<<<512, 256, 0, stream>>>(ws);
    k3_reassemble<<<dim3(256, 4), 256, 0, stream>>>(x, ws, out);
}

// Round 5
// 137.343 us; speedup vs baseline: 1.0930x; 1.0930x over previous
//
#include <hip/hip_runtime.h>
#include <hip/hip_bf16.h>

// CARAFE fused: B=4, C=128, H=W=64, C_MID=64, S=2, K=5
#define HW 4096

typedef __attribute__((ext_vector_type(8))) short  short8;   // 8 bf16 (4 VGPRs)
typedef __attribute__((ext_vector_type(4))) float  floatx4;  // MFMA C/D

// workspace (BYTE offsets): only prepped weights now
#define OFF_W1T 0ul        // float[128*64] = 32768 B   w1t[c][o]
#define OFF_W2B 32768ul    // bf16 [112*576]= 129024 B  w2b[n][k], k = tap*64 + c

// ---------------- prep: w1 transpose + w2 -> bf16 [n][k] ----------------
__global__ __launch_bounds__(256) void prep_kernel(const float* __restrict__ w1,
                                                   const float* __restrict__ w2,
                                                   char* __restrict__ ws) {
    int tid = blockIdx.x * 256 + threadIdx.x;
    if (tid < 8192) {
        int o = tid & 63, c = tid >> 6;
        ((float*)(ws + OFF_W1T))[c * 64 + o] = w1[o * 128 + c];
    } else if (tid < 8192 + 112 * 576) {
        int i = tid - 8192;
        int n = i / 576;          // 0..111 (100..111 zero pad)
        int k = i - n * 576;      // k = t*64 + c
        int t = k >> 6, c = k & 63;
        float v = (n < 100) ? w2[(n * 64 + c) * 9 + t] : 0.f;
        ((__hip_bfloat16*)(ws + OFF_W2B))[i] = __float2bfloat16(v);
    }
}

// ---------------- fused CARAFE: one block per (b, 8x8 tile), 1024 threads = 16 waves --------
__global__ __launch_bounds__(1024, 1) void fused_carafe(const float* __restrict__ x,
                                                        const char* __restrict__ ws,
                                                        const float* __restrict__ gamma,
                                                        const float* __restrict__ beta,
                                                        const float* __restrict__ mean,
                                                        const float* __restrict__ var,
                                                        float* __restrict__ out) {
    __shared__ float xs[128 * 144];                       // x halo 12x12 x 128ch, 73.7 KB
    __shared__ __align__(16) __hip_bfloat16 hs[100 * 88]; // h halo 10x10 x 64ch, 17.6 KB
    __shared__ float lg[64 * 114];                        // logits [pix][n], 29.2 KB
    __shared__ float ks[6400];                            // softmaxed ker [t*4+g][pix], 25.6 KB

    int b    = blockIdx.x >> 6;
    int tile = blockIdx.x & 63;
    int ty0 = (tile >> 3) << 3;
    int tx0 = (tile & 7) << 3;
    int tid = threadIdx.x;
    int lane = tid & 63, wave = tid >> 6;

    // ---- phase A: stage x 12x12 halo, 128 ch, zero-padded ----
    const float* xb = x + (size_t)b * 128 * HW;
    #pragma unroll
    for (int i = 0; i < 18; ++i) {
        int idx = tid + i * 1024;                 // 18432 = 128*144
        int c = idx / 144, p = idx - c * 144;
        int hy = p / 12, hx = p - hy * 12;
        int gy = ty0 + hy - 2, gx = tx0 + hx - 2;
        float v = 0.f;
        if ((unsigned)gy < 64u && (unsigned)gx < 64u)
            v = xb[(size_t)c * HW + gy * 64 + gx];
        xs[idx] = v;
    }
    __syncthreads();

    // ---- phase B: h = relu(bn(w1 @ x)) on 10x10 halo -> hs (bf16), 0 outside image ----
    {
        int og = wave & 7, o0 = og * 8;
        int hp = (wave >> 3) * 64 + lane;         // halo pixel 0..127 (100 real)
        if (hp < 100) {
            int hy = hp / 10, hx = hp - hy * 10;
            int gy = ty0 + hy - 1, gx = tx0 + hx - 1;
            if ((unsigned)gy < 64u && (unsigned)gx < 64u) {
                int p12 = (hy + 1) * 12 + (hx + 1);
                const float* w1t = (const float*)(ws + OFF_W1T);
                float acc[8];
                #pragma unroll
                for (int j = 0; j < 8; ++j) acc[j] = 0.f;
                for (int c = 0; c < 128; ++c) {
                    float xv = xs[c * 144 + p12];
                    const float* wr = w1t + c * 64 + o0;   // wave-uniform -> s_load
                    #pragma unroll
                    for (int j = 0; j < 8; ++j) acc[j] = fmaf(wr[j], xv, acc[j]);
                }
                union { uint4 v; __hip_bfloat16 h[8]; } u;
                #pragma unroll
                for (int j = 0; j < 8; ++j) {
                    int o = o0 + j;
                    float inv = gamma[o] * rsqrtf(var[o] + 1e-5f);
                    float add = beta[o] - mean[o] * inv;
                    u.h[j] = __float2bfloat16(fmaxf(fmaf(acc[j], inv, add), 0.f));
                }
                *(uint4*)(&hs[hp * 88 + o0]) = u.v;
            } else {
                *(uint4*)(&hs[hp * 88 + o0]) = make_uint4(0u, 0u, 0u, 0u); // conv zero-pad
            }
        }
    }
    __syncthreads();

    // ---- phase C: 3x3 conv as bf16 MFMA GEMM: M=64 pix, N=112, K=576 ----
    {
        int mt = wave & 3, ng = wave >> 2;        // 4 M-tiles x 4 N-groups
        int q = lane >> 4, m = lane & 15;
        int pixidx = mt * 16 + m;
        int py = pixidx >> 3, px = pixidx & 7;
        int nt0 = ng * 2;
        int NT = (ng < 3) ? 2 : 1;                // N-tiles {0,1}{2,3}{4,5}{6}

        const __hip_bfloat16* w2b = (const __hip_bfloat16*)(ws + OFF_W2B);
        const __hip_bfloat16* bp0 = w2b + (size_t)(nt0 * 16 + m) * 576 + q * 8;
        const __hip_bfloat16* bp1 = w2b + (size_t)((nt0 + 1) * 16 + m) * 576 + q * 8;

        floatx4 acc0, acc1;
        #pragma unroll
        for (int r = 0; r < 4; ++r) { acc0[r] = 0.f; acc1[r] = 0.f; }

        short8 b0 = *(const short8*)bp0;
        short8 b1 = (NT == 2) ? *(const short8*)bp1 : b0;

        for (int s = 0; s < 18; ++s) {
            int t = s >> 1, c0 = (s & 1) * 32;
            short8 a = *(const short8*)(&hs[((py + t / 3) * 10 + (px + t % 3)) * 88 + c0 + q * 8]);
            short8 n0 = b0, n1 = b1;
            if (s < 17) {
                int ko = (s + 1) * 32;
                n0 = *(const short8*)(bp0 + ko);
                if (NT == 2) n1 = *(const short8*)(bp1 + ko);
            }
            acc0 = __builtin_amdgcn_mfma_f32_16x16x32_bf16(a, b0, acc0, 0, 0, 0);
            if (NT == 2)
                acc1 = __builtin_amdgcn_mfma_f32_16x16x32_bf16(a, b1, acc1, 0, 0, 0);
            b0 = n0; b1 = n1;
        }
        // C/D: col=lane&15 (n within tile), row=q*4+r (pixel within M-tile)
        #pragma unroll
        for (int r = 0; r < 4; ++r)
            lg[(mt * 16 + q * 4 + r) * 114 + nt0 * 16 + m] = acc0[r];
        if (NT == 2) {
            #pragma unroll
            for (int r = 0; r < 4; ++r)
                lg[(mt * 16 + q * 4 + r) * 114 + (nt0 + 1) * 16 + m] = acc1[r];
        }
    }
    __syncthreads();

    // ---- phase D: softmax over 25 taps, ker -> LDS ----
    if (tid < 256) {
        int pix = tid & 63, g = tid >> 6;
        float v[25];
        #pragma unroll
        for (int wi = 0; wi < 25; ++wi) v[wi] = lg[pix * 114 + g * 25 + wi];
        float mx = v[0];
        #pragma unroll
        for (int wi = 1; wi < 25; ++wi) mx = fmaxf(mx, v[wi]);
        float ssum = 0.f;
        #pragma unroll
        for (int wi = 0; wi < 25; ++wi) { v[wi] = __expf(v[wi] - mx); ssum += v[wi]; }
        float rs = 1.f / ssum;
        #pragma unroll
        for (int t25 = 0; t25 < 25; ++t25)
            ks[(t25 * 4 + g) * 64 + pix] = v[t25] * rs;
    }
    __syncthreads();

    // ---- phase E: 5x5 reassembly + pixel shuffle; wave = 8 channels, lane = pixel ----
    {
        int ch0 = wave * 8;
        int py = lane >> 3, px = lane & 7;
        int Y = ty0 + py, X = tx0 + px;

        float acc[32];  // [8 ch][4 g]
        #pragma unroll
        for (int i = 0; i < 32; ++i) acc[i] = 0.f;

        const float* xw = xs + ch0 * 144 + py * 12 + px;
        #pragma unroll 5
        for (int t = 0; t < 25; ++t) {
            int ti = t / 5, tj = t % 5;
            int po = ti * 12 + tj;
            float k0 = ks[(t * 4 + 0) * 64 + lane];
            float k1 = ks[(t * 4 + 1) * 64 + lane];
            float k2 = ks[(t * 4 + 2) * 64 + lane];
            float k3 = ks[(t * 4 + 3) * 64 + lane];
            #pragma unroll
            for (int i = 0; i < 8; ++i) {
                float xv = xw[i * 144 + po];
                acc[i * 4 + 0] = fmaf(xv, k0, acc[i * 4 + 0]);
                acc[i * 4 + 1] = fmaf(xv, k1, acc[i * 4 + 1]);
                acc[i * 4 + 2] = fmaf(xv, k2, acc[i * 4 + 2]);
                acc[i * 4 + 3] = fmaf(xv, k3, acc[i * 4 + 3]);
            }
        }

        #pragma unroll
        for (int i = 0; i < 8; ++i) {
            size_t o0 = (((size_t)b * 128 + ch0 + i) * 128 + 2 * Y) * 128 + 2 * X;
            *(float2*)(out + o0)       = make_float2(acc[i * 4 + 0], acc[i * 4 + 1]);
            *(float2*)(out + o0 + 128) = make_float2(acc[i * 4 + 2], acc[i * 4 + 3]);
        }
    }
}

extern "C" void kernel_launch(void* const* d_in, const int* in_sizes, int n_in,
                              void* d_out, int out_size, void* d_ws, size_t ws_size,
                              hipStream_t stream) {
    const float* x     = (const float*)d_in[0];
    const float* w1    = (const float*)d_in[1];
    const float* w2    = (const float*)d_in[2];
    const float* gamma = (const float*)d_in[3];
    const float* beta  = (const float*)d_in[4];
    const float* mean  = (const float*)d_in[5];
    const float* var   = (const float*)d_in[6];
    float* out = (float*)d_out;
    char*  ws  = (char*)d_ws;

    prep_kernel<<<284, 256, 0, stream>>>(w1, w2, ws);
    fused_carafe<<<256, 1024, 0, stream>>>(x, ws, gamma, beta, mean, var, out);
}

// Round 6
// 114.202 us; speedup vs baseline: 1.3145x; 1.2026x over previous
//
#include <hip/hip_runtime.h>
#include <hip/hip_bf16.h>

// CARAFE fused: B=4, C=128, H=W=64, C_MID=64, S=2, K=5
#define HW 4096

typedef __attribute__((ext_vector_type(8))) short  short8;   // 8 bf16 (4 VGPRs)
typedef __attribute__((ext_vector_type(4))) float  floatx4;  // MFMA C/D

// workspace (BYTE offsets)
#define OFF_W2B 0ul        // bf16 [112][576]  = 129024 B   w2b[n][k], k = tap*64 + c
#define OFF_W1B 129024ul   // bf16 [64][128]   = 16384 B    w1b[o][c]
#define OFF_BN  145408ul   // float2[64]       = 512 B      (inv, add) per o

// ---------------- prep: w2 -> bf16 [n][k]; w1 -> bf16 [o][c]; BN folded ----------------
__global__ __launch_bounds__(256) void prep_kernel(const float* __restrict__ w1,
                                                   const float* __restrict__ w2,
                                                   const float* __restrict__ gamma,
                                                   const float* __restrict__ beta,
                                                   const float* __restrict__ mean,
                                                   const float* __restrict__ var,
                                                   char* __restrict__ ws) {
    int tid = blockIdx.x * 256 + threadIdx.x;
    if (tid < 64512) {
        int n = tid / 576;
        int k = tid - n * 576;       // k = t*64 + c
        int t = k >> 6, c = k & 63;
        float v = (n < 100) ? w2[(n * 64 + c) * 9 + t] : 0.f;
        ((__hip_bfloat16*)(ws + OFF_W2B))[tid] = __float2bfloat16(v);
    } else if (tid < 64512 + 8192) {
        int i = tid - 64512;         // same [o][c] layout as input
        ((__hip_bfloat16*)(ws + OFF_W1B))[i] = __float2bfloat16(w1[i]);
    } else if (tid < 64512 + 8192 + 64) {
        int o = tid - 64512 - 8192;
        float inv = gamma[o] * rsqrtf(var[o] + 1e-5f);
        ((float2*)(ws + OFF_BN))[o] = make_float2(inv, beta[o] - mean[o] * inv);
    }
}

// ---------------- fused CARAFE: one block per (b, 8x8 tile), 1024 threads = 16 waves --------
__global__ __launch_bounds__(1024, 1) void fused_carafe(const float* __restrict__ x,
                                                        const char* __restrict__ ws,
                                                        float* __restrict__ out) {
    __shared__ float xs[128 * 144];                       // x halo 12x12 x 128ch fp32, 73.7 KB
    __shared__ __align__(16) __hip_bfloat16 hs[100 * 88]; // h halo 10x10 x 64ch bf16, 17.6 KB
    __shared__ __align__(16) char un[54784];              // union: xbh | (lg + ks)
    __hip_bfloat16* xbh = (__hip_bfloat16*)un;            // [112][136] bf16 (phase A/B only)
    float* lg = (float*)un;                               // [64][114] logits (phase C/D)
    float* ks = (float*)(un + 29184);                     // [100*64] softmaxed ker (phase D/E)

    int b    = blockIdx.x >> 6;
    int tile = blockIdx.x & 63;
    int ty0 = (tile >> 3) << 3;
    int tx0 = (tile & 7) << 3;
    int tid = threadIdx.x;
    int lane = tid & 63, wave = tid >> 6;
    int q = lane >> 4, m = lane & 15;

    // ---- preload phase-B B-fragments (w1 bf16) into VGPRs: no LDS/barrier dependency ----
    int nh  = wave & 1;            // N-half for phase B
    int nt0 = nh * 2;
    const __hip_bfloat16* w1b = (const __hip_bfloat16*)(ws + OFF_W1B);
    short8 bw[2][4];
    #pragma unroll
    for (int j = 0; j < 2; ++j)
        #pragma unroll
        for (int s = 0; s < 4; ++s)
            bw[j][s] = *(const short8*)(w1b + ((nt0 + j) * 16 + m) * 128 + s * 32 + q * 8);

    // ---- phase A: stage x 12x12 halo fp32 + bf16 copy of 10x10 interior into xbh ----
    const float* xb = x + (size_t)b * 128 * HW;
    #pragma unroll
    for (int i = 0; i < 18; ++i) {
        int idx = tid + i * 1024;                 // 18432 = 128*144
        int c = idx / 144, p = idx - c * 144;
        int hy = p / 12, hx = p - hy * 12;
        int gy = ty0 + hy - 2, gx = tx0 + hx - 2;
        float v = 0.f;
        if ((unsigned)gy < 64u && (unsigned)gx < 64u)
            v = xb[(size_t)c * HW + gy * 64 + gx];
        xs[idx] = v;
        // interior 10x10 -> xbh[hp][c]
        if ((unsigned)(hy - 1) < 10u && (unsigned)(hx - 1) < 10u) {
            int hp = (hy - 1) * 10 + (hx - 1);
            xbh[hp * 136 + c] = __float2bfloat16(v);
        }
    }
    // zero xbh pad rows 100..111 (12*136 = 1632 bf16 = 816 dwords)
    if (tid < 816) ((unsigned*)(xbh + 100 * 136))[tid] = 0u;
    __syncthreads();

    // ---- phase B: h = relu(bn(w1 @ x)) via MFMA: M=112 pix, N=64, K=128 ----
    if (wave < 14) {
        int mt = wave >> 1;                       // 7 M-tiles
        int pix = mt * 16 + m;
        floatx4 acc0, acc1;
        #pragma unroll
        for (int r = 0; r < 4; ++r) { acc0[r] = 0.f; acc1[r] = 0.f; }
        #pragma unroll
        for (int s = 0; s < 4; ++s) {
            short8 a = *(const short8*)(&xbh[pix * 136 + s * 32 + q * 8]);
            acc0 = __builtin_amdgcn_mfma_f32_16x16x32_bf16(a, bw[0][s], acc0, 0, 0, 0);
            acc1 = __builtin_amdgcn_mfma_f32_16x16x32_bf16(a, bw[1][s], acc1, 0, 0, 0);
        }
        // epilogue: BN + ReLU, mask out-of-image, store bf16 to hs
        const float2* bn = (const float2*)(ws + OFF_BN);
        int o0 = nt0 * 16 + m, o1 = (nt0 + 1) * 16 + m;
        float2 ia0 = bn[o0], ia1 = bn[o1];
        #pragma unroll
        for (int r = 0; r < 4; ++r) {
            int prow = mt * 16 + q * 4 + r;       // halo pixel index
            if (prow < 100) {
                int hy = prow / 10, hx = prow - hy * 10;
                int gy = ty0 + hy - 1, gx = tx0 + hx - 1;
                bool in = ((unsigned)gy < 64u) && ((unsigned)gx < 64u);
                float v0 = in ? fmaxf(fmaf(acc0[r], ia0.x, ia0.y), 0.f) : 0.f;
                float v1 = in ? fmaxf(fmaf(acc1[r], ia1.x, ia1.y), 0.f) : 0.f;
                hs[prow * 88 + o0] = __float2bfloat16(v0);
                hs[prow * 88 + o1] = __float2bfloat16(v1);
            }
        }
    }
    __syncthreads();

    // ---- phase C: 3x3 conv as bf16 MFMA GEMM: M=64 pix, N=112, K=576 ----
    {
        int mt = wave & 3, ng = wave >> 2;        // 4 M-tiles x 4 N-groups
        int pixidx = mt * 16 + m;
        int py = pixidx >> 3, px = pixidx & 7;
        int cn0 = ng * 2;
        int NT = (ng < 3) ? 2 : 1;                // N-tiles {0,1}{2,3}{4,5}{6}

        const __hip_bfloat16* w2b = (const __hip_bfloat16*)(ws + OFF_W2B);
        const __hip_bfloat16* bp0 = w2b + (size_t)(cn0 * 16 + m) * 576 + q * 8;
        const __hip_bfloat16* bp1 = w2b + (size_t)((cn0 + 1) * 16 + m) * 576 + q * 8;

        floatx4 acc0, acc1;
        #pragma unroll
        for (int r = 0; r < 4; ++r) { acc0[r] = 0.f; acc1[r] = 0.f; }

        short8 b0 = *(const short8*)bp0;
        short8 b1 = (NT == 2) ? *(const short8*)bp1 : b0;

        for (int s = 0; s < 18; ++s) {
            int t = s >> 1, c0 = (s & 1) * 32;
            short8 a = *(const short8*)(&hs[((py + t / 3) * 10 + (px + t % 3)) * 88 + c0 + q * 8]);
            short8 n0 = b0, n1 = b1;
            if (s < 17) {
                int ko = (s + 1) * 32;
                n0 = *(const short8*)(bp0 + ko);
                if (NT == 2) n1 = *(const short8*)(bp1 + ko);
            }
            acc0 = __builtin_amdgcn_mfma_f32_16x16x32_bf16(a, b0, acc0, 0, 0, 0);
            if (NT == 2)
                acc1 = __builtin_amdgcn_mfma_f32_16x16x32_bf16(a, b1, acc1, 0, 0, 0);
            b0 = n0; b1 = n1;
        }
        #pragma unroll
        for (int r = 0; r < 4; ++r)
            lg[(mt * 16 + q * 4 + r) * 114 + cn0 * 16 + m] = acc0[r];
        if (NT == 2) {
            #pragma unroll
            for (int r = 0; r < 4; ++r)
                lg[(mt * 16 + q * 4 + r) * 114 + (cn0 + 1) * 16 + m] = acc1[r];
        }
    }
    __syncthreads();

    // ---- phase D: softmax over 25 taps, ker -> LDS ----
    if (tid < 256) {
        int pix = tid & 63, g = tid >> 6;
        float v[25];
        #pragma unroll
        for (int wi = 0; wi < 25; ++wi) v[wi] = lg[pix * 114 + g * 25 + wi];
        float mx = v[0];
        #pragma unroll
        for (int wi = 1; wi < 25; ++wi) mx = fmaxf(mx, v[wi]);
        float ssum = 0.f;
        #pragma unroll
        for (int wi = 0; wi < 25; ++wi) { v[wi] = __expf(v[wi] - mx); ssum += v[wi]; }
        float rs = 1.f / ssum;
        #pragma unroll
        for (int t25 = 0; t25 < 25; ++t25)
            ks[(t25 * 4 + g) * 64 + pix] = v[t25] * rs;
    }
    __syncthreads();

    // ---- phase E: 5x5 reassembly + pixel shuffle; wave = 8 channels, lane = pixel ----
    {
        int ch0 = wave * 8;
        int py = lane >> 3, px = lane & 7;
        int Y = ty0 + py, X = tx0 + px;

        float acc[32];  // [8 ch][4 g]
        #pragma unroll
        for (int i = 0; i < 32; ++i) acc[i] = 0.f;

        const float* xw = xs + ch0 * 144 + py * 12 + px;
        #pragma unroll 5
        for (int t = 0; t < 25; ++t) {
            int ti = t / 5, tj = t % 5;
            int po = ti * 12 + tj;
            float k0 = ks[(t * 4 + 0) * 64 + lane];
            float k1 = ks[(t * 4 + 1) * 64 + lane];
            float k2 = ks[(t * 4 + 2) * 64 + lane];
            float k3 = ks[(t * 4 + 3) * 64 + lane];
            #pragma unroll
            for (int i = 0; i < 8; ++i) {
                float xv = xw[i * 144 + po];
                acc[i * 4 + 0] = fmaf(xv, k0, acc[i * 4 + 0]);
                acc[i * 4 + 1] = fmaf(xv, k1, acc[i * 4 + 1]);
                acc[i * 4 + 2] = fmaf(xv, k2, acc[i * 4 + 2]);
                acc[i * 4 + 3] = fmaf(xv, k3, acc[i * 4 + 3]);
            }
        }

        #pragma unroll
        for (int i = 0; i < 8; ++i) {
            size_t o0 = (((size_t)b * 128 + ch0 + i) * 128 + 2 * Y) * 128 + 2 * X;
            *(float2*)(out + o0)       = make_float2(acc[i * 4 + 0], acc[i * 4 + 1]);
            *(float2*)(out + o0 + 128) = make_float2(acc[i * 4 + 2], acc[i * 4 + 3]);
        }
    }
}

extern "C" void kernel_launch(void* const* d_in, const int* in_sizes, int n_in,
                              void* d_out, int out_size, void* d_ws, size_t ws_size,
                              hipStream_t stream) {
    const float* x     = (const float*)d_in[0];
    const float* w1    = (const float*)d_in[1];
    const float* w2    = (const float*)d_in[2];
    const float* gamma = (const float*)d_in[3];
    const float* beta  = (const float*)d_in[4];
    const float* mean  = (const float*)d_in[5];
    const float* var   = (const float*)d_in[6];
    float* out = (float*)d_out;
    char*  ws  = (char*)d_ws;

    prep_kernel<<<285, 256, 0, stream>>>(w1, w2, gamma, beta, mean, var, ws);
    fused_carafe<<<256, 1024, 0, stream>>>(x, ws, out);
}

// Round 7
// 108.814 us; speedup vs baseline: 1.3796x; 1.0495x over previous
//
#include <hip/hip_runtime.h>
#include <hip/hip_bf16.h>

// CARAFE fused: B=4, C=128, H=W=64, C_MID=64, S=2, K=5
#define HW 4096

typedef __attribute__((ext_vector_type(8))) short  short8;   // 8 bf16 (4 VGPRs)
typedef __attribute__((ext_vector_type(4))) float  floatx4;  // MFMA C/D

// workspace (BYTE offsets)
#define OFF_W2B 0ul        // bf16 [112][576]  = 129024 B   w2b[n][k], k = tap*64 + c
#define OFF_W1B 129024ul   // bf16 [64][128]   = 16384 B    w1b[o][c]
#define OFF_BN  145408ul   // float2[64]       = 512 B      (inv, add) per o

__device__ __forceinline__ float bfbits(unsigned u) {
    union { unsigned u; float f; } t; t.u = u; return t.f;
}

// ---------------- prep: w2 -> bf16 [n][k]; w1 -> bf16 [o][c]; BN folded ----------------
__global__ __launch_bounds__(256) void prep_kernel(const float* __restrict__ w1,
                                                   const float* __restrict__ w2,
                                                   const float* __restrict__ gamma,
                                                   const float* __restrict__ beta,
                                                   const float* __restrict__ mean,
                                                   const float* __restrict__ var,
                                                   char* __restrict__ ws) {
    int tid = blockIdx.x * 256 + threadIdx.x;
    if (tid < 64512) {
        int n = tid / 576;
        int k = tid - n * 576;       // k = t*64 + c
        int t = k >> 6, c = k & 63;
        float v = (n < 100) ? w2[(n * 64 + c) * 9 + t] : 0.f;
        ((__hip_bfloat16*)(ws + OFF_W2B))[tid] = __float2bfloat16(v);
    } else if (tid < 64512 + 8192) {
        int i = tid - 64512;         // same [o][c] layout as input
        ((__hip_bfloat16*)(ws + OFF_W1B))[i] = __float2bfloat16(w1[i]);
    } else if (tid < 64512 + 8192 + 64) {
        int o = tid - 64512 - 8192;
        float inv = gamma[o] * rsqrtf(var[o] + 1e-5f);
        ((float2*)(ws + OFF_BN))[o] = make_float2(inv, beta[o] - mean[o] * inv);
    }
}

// ---------------- fused CARAFE: one block per (b, 4x8 tile), 1024 threads = 16 waves --------
// grid 512 = b(4) x tile(128); LDS 61 KB -> 2 blocks/CU, full 32-wave residency
__global__ __launch_bounds__(1024, 8) void fused_carafe(const float* __restrict__ x,
                                                        const char* __restrict__ ws,
                                                        float* __restrict__ out) {
    __shared__ __align__(16) __hip_bfloat16 xs[96 * 136];  // x halo 8x12 [pix][c], 26.1 KB
    __shared__ __align__(16) __hip_bfloat16 hs[60 * 72];   // h halo 6x10 [pix][c],  8.6 KB
    __shared__ __align__(16) float lg[32 * 114];           // logits [pix][n],      14.6 KB
    __shared__ __align__(16) float ks[32 * 104];           // ker [pix][t*4+g],     13.3 KB

    int b    = blockIdx.x >> 7;
    int tile = blockIdx.x & 127;
    int ty0 = (tile >> 3) * 4;
    int tx0 = (tile & 7) * 8;
    int tid = threadIdx.x;
    int lane = tid & 63, wave = tid >> 6;
    int q = lane >> 4, m = lane & 15;

    // ---- preload phase-B B-frags (w1) + BN pair: no dependency on LDS ----
    int bnt = wave >> 2;                      // phase-B N-tile 0..3
    int bo  = bnt * 16 + m;                   // phase-B output channel
    const __hip_bfloat16* w1b = (const __hip_bfloat16*)(ws + OFF_W1B);
    short8 bw[4];
    #pragma unroll
    for (int s = 0; s < 4; ++s)
        bw[s] = *(const short8*)(w1b + bo * 128 + s * 32 + q * 8);
    float2 bnia = ((const float2*)(ws + OFF_BN))[bo];

    // ---- phase A: stage x 8x12 halo as bf16 [pix][c], zero-padded ----
    const float* xb = x + (size_t)b * 128 * HW;
    #pragma unroll
    for (int i = 0; i < 12; ++i) {
        int idx = tid + i * 1024;             // 12288 = 128 * 96
        int c = idx / 96, p = idx - c * 96;
        int hy = p / 12, hx = p - hy * 12;
        int gy = ty0 + hy - 2, gx = tx0 + hx - 2;
        float v = 0.f;
        if ((unsigned)gy < 64u && (unsigned)gx < 64u)
            v = xb[(size_t)c * HW + gy * 64 + gx];
        xs[p * 136 + c] = __float2bfloat16(v);
    }
    __syncthreads();

    // ---- phase B: h = relu(bn(w1 @ x)) via MFMA: M=64(60) halo pix, N=64, K=128 ----
    {
        int mt = wave & 3;                    // 4 M-tiles x 4 N-tiles = 16 waves
        int hp = mt * 16 + m;                 // halo pixel for A-frag row
        int hy1 = hp / 10, hx1 = hp - hy1 * 10;
        int xrow = (hy1 + 1) * 12 + (hx1 + 1);  // rows 60..63 read garbage, masked below
        floatx4 acc;
        #pragma unroll
        for (int r = 0; r < 4; ++r) acc[r] = 0.f;
        #pragma unroll
        for (int s = 0; s < 4; ++s) {
            short8 a = *(const short8*)(&xs[xrow * 136 + s * 32 + q * 8]);
            acc = __builtin_amdgcn_mfma_f32_16x16x32_bf16(a, bw[s], acc, 0, 0, 0);
        }
        #pragma unroll
        for (int r = 0; r < 4; ++r) {
            int prow = mt * 16 + q * 4 + r;
            if (prow < 60) {
                int phy = prow / 10, phx = prow - phy * 10;
                int gy = ty0 + phy - 1, gx = tx0 + phx - 1;
                bool in = ((unsigned)gy < 64u) && ((unsigned)gx < 64u);
                float v = in ? fmaxf(fmaf(acc[r], bnia.x, bnia.y), 0.f) : 0.f;
                hs[prow * 72 + bo] = __float2bfloat16(v);
            }
        }
    }
    __syncthreads();

    // ---- phase C: 3x3 conv via MFMA: M=32 pix, N=112, K=576 ----
    {
        int mt = wave & 1, nt = wave >> 1;    // 2 M-tiles x 8 N-slots (nt=7 idle)
        if (nt < 7) {
            int pixidx = mt * 16 + m;
            int py = pixidx >> 3, px = pixidx & 7;
            const __hip_bfloat16* w2b = (const __hip_bfloat16*)(ws + OFF_W2B);
            const __hip_bfloat16* bp  = w2b + (size_t)(nt * 16 + m) * 576 + q * 8;

            floatx4 acc;
            #pragma unroll
            for (int r = 0; r < 4; ++r) acc[r] = 0.f;

            short8 bcur = *(const short8*)bp;
            for (int s = 0; s < 18; ++s) {
                int t = s >> 1, c0 = (s & 1) * 32;
                int ti = t / 3, tj = t - ti * 3;
                short8 a = *(const short8*)(&hs[((py + ti) * 10 + px + tj) * 72 + c0 + q * 8]);
                short8 bn2 = bcur;
                if (s < 17) bn2 = *(const short8*)(bp + (s + 1) * 32);
                acc = __builtin_amdgcn_mfma_f32_16x16x32_bf16(a, bcur, acc, 0, 0, 0);
                bcur = bn2;
            }
            #pragma unroll
            for (int r = 0; r < 4; ++r)
                lg[(mt * 16 + q * 4 + r) * 114 + nt * 16 + m] = acc[r];
        }
    }
    __syncthreads();

    // ---- phase D: softmax over 25 taps -> ks [pix][t*4+g] ----
    if (tid < 128) {
        int pix = tid & 31, g = tid >> 5;
        float v[25];
        #pragma unroll
        for (int wi = 0; wi < 25; ++wi) v[wi] = lg[pix * 114 + g * 25 + wi];
        float mx = v[0];
        #pragma unroll
        for (int wi = 1; wi < 25; ++wi) mx = fmaxf(mx, v[wi]);
        float ssum = 0.f;
        #pragma unroll
        for (int wi = 0; wi < 25; ++wi) { v[wi] = __expf(v[wi] - mx); ssum += v[wi]; }
        float rs = 1.f / ssum;
        #pragma unroll
        for (int t25 = 0; t25 < 25; ++t25)
            ks[pix * 104 + t25 * 4 + g] = v[t25] * rs;
    }
    __syncthreads();

    // ---- phase E: 5x5 reassembly + pixel shuffle ----
    // wave = 8-ch block; lane = (pix 0..31, chsub 0..1); thread: 4 ch x 4 g
    {
        int pix   = lane & 31;
        int chsub = lane >> 5;
        int chb   = wave * 8 + chsub * 4;
        int py = pix >> 3, px = pix & 7;
        int Y = ty0 + py, X = tx0 + px;

        float acc[16];  // [4 ch][4 g]
        #pragma unroll
        for (int i = 0; i < 16; ++i) acc[i] = 0.f;

        #pragma unroll 5
        for (int t = 0; t < 25; ++t) {
            int ti = t / 5, tj = t - ti * 5;
            int xrow = (py + ti) * 12 + (px + tj);
            uint2 xv = *(const uint2*)(&xs[xrow * 136 + chb]);     // 4 bf16 ch
            float4 kv = *(const float4*)(&ks[pix * 104 + t * 4]);  // 4 groups
            float xf[4];
            xf[0] = bfbits(xv.x << 16);
            xf[1] = bfbits(xv.x & 0xFFFF0000u);
            xf[2] = bfbits(xv.y << 16);
            xf[3] = bfbits(xv.y & 0xFFFF0000u);
            #pragma unroll
            for (int i = 0; i < 4; ++i) {
                acc[i * 4 + 0] = fmaf(xf[i], kv.x, acc[i * 4 + 0]);
                acc[i * 4 + 1] = fmaf(xf[i], kv.y, acc[i * 4 + 1]);
                acc[i * 4 + 2] = fmaf(xf[i], kv.z, acc[i * 4 + 2]);
                acc[i * 4 + 3] = fmaf(xf[i], kv.w, acc[i * 4 + 3]);
            }
        }

        #pragma unroll
        for (int i = 0; i < 4; ++i) {
            size_t o0 = (((size_t)b * 128 + chb + i) * 128 + 2 * Y) * 128 + 2 * X;
            *(float2*)(out + o0)       = make_float2(acc[i * 4 + 0], acc[i * 4 + 1]);
            *(float2*)(out + o0 + 128) = make_float2(acc[i * 4 + 2], acc[i * 4 + 3]);
        }
    }
}

extern "C" void kernel_launch(void* const* d_in, const int* in_sizes, int n_in,
                              void* d_out, int out_size, void* d_ws, size_t ws_size,
                              hipStream_t stream) {
    const float* x     = (const float*)d_in[0];
    const float* w1    = (const float*)d_in[1];
    const float* w2    = (const float*)d_in[2];
    const float* gamma = (const float*)d_in[3];
    const float* beta  = (const float*)d_in[4];
    const float* mean  = (const float*)d_in[5];
    const float* var   = (const float*)d_in[6];
    float* out = (float*)d_out;
    char*  ws  = (char*)d_ws;

    prep_kernel<<<285, 256, 0, stream>>>(w1, w2, gamma, beta, mean, var, ws);
    fused_carafe<<<512, 1024, 0, stream>>>(x, ws, out);
}

// Round 8
// 105.907 us; speedup vs baseline: 1.4175x; 1.0274x over previous
//
#include <hip/hip_runtime.h>
#include <hip/hip_bf16.h>

// CARAFE fused: B=4, C=128, H=W=64, C_MID=64, S=2, K=5
#define HW 4096

typedef __attribute__((ext_vector_type(8))) short  short8;   // 8 bf16 (4 VGPRs)
typedef __attribute__((ext_vector_type(4))) float  floatx4;  // MFMA C/D

// workspace (BYTE offsets)
#define OFF_W2B 0ul        // bf16 [112][576]  = 129024 B   w2b[n][k], k = tap*64 + c
#define OFF_W1B 129024ul   // bf16 [64][128]   = 16384 B    w1b[o][c]
#define OFF_BN  145408ul   // float2[64]       = 512 B      (inv, add) per o
#define OFF_XG  145920ul   // bf16 [4][16][4096][8] = 4 MB  x transposed: [b][cq][pix][8c]

__device__ __forceinline__ float bfbits(unsigned u) {
    union { unsigned u; float f; } t; t.u = u; return t.f;
}

// ---------------- prep: x -> bf16 [b][cq][pix][8]; w2 -> bf16 [n][k]; w1 bf16; BN folded ----
__global__ __launch_bounds__(256) void prep_kernel(const float* __restrict__ x,
                                                   const float* __restrict__ w1,
                                                   const float* __restrict__ w2,
                                                   const float* __restrict__ gamma,
                                                   const float* __restrict__ beta,
                                                   const float* __restrict__ mean,
                                                   const float* __restrict__ var,
                                                   char* __restrict__ ws) {
    int tid = blockIdx.x * 256 + threadIdx.x;
    if (tid < 262144) {
        // xg[tid][0..7] = x[b][cq*8+cc][pix], tid = (b*16+cq)*4096 + pix
        int pix = tid & 4095;
        int cq  = (tid >> 12) & 15;
        int b   = tid >> 16;
        const float* xp = x + ((size_t)(b * 128 + cq * 8)) * HW + pix;
        union { short8 s; __hip_bfloat16 h[8]; } u;
        #pragma unroll
        for (int cc = 0; cc < 8; ++cc) u.h[cc] = __float2bfloat16(xp[(size_t)cc * HW]);
        *(short8*)((__hip_bfloat16*)(ws + OFF_XG) + (size_t)tid * 8) = u.s;
        return;
    }
    int t2 = tid - 262144;
    if (t2 < 64512) {
        int n = t2 / 576;
        int k = t2 - n * 576;        // k = tap*64 + c
        int t = k >> 6, c = k & 63;
        float v = (n < 100) ? w2[(n * 64 + c) * 9 + t] : 0.f;
        ((__hip_bfloat16*)(ws + OFF_W2B))[t2] = __float2bfloat16(v);
    } else if (t2 < 64512 + 8192) {
        int i = t2 - 64512;
        ((__hip_bfloat16*)(ws + OFF_W1B))[i] = __float2bfloat16(w1[i]);
    } else if (t2 < 64512 + 8192 + 64) {
        int o = t2 - 64512 - 8192;
        float inv = gamma[o] * rsqrtf(var[o] + 1e-5f);
        ((float2*)(ws + OFF_BN))[o] = make_float2(inv, beta[o] - mean[o] * inv);
    }
}

// ---------------- fused CARAFE: one block per (b, 4x8 tile), 1024 threads = 16 waves --------
// grid 512; LDS 61 KB; 16-wave blocks -> 2 blocks/CU (wave-capped), full 32-wave residency
__global__ __launch_bounds__(1024, 8) void fused_carafe(const char* __restrict__ ws,
                                                        float* __restrict__ out) {
    __shared__ __align__(16) __hip_bfloat16 xs[1536 * 8];  // x halo [cq16][pix96][8c], 24.6 KB
    __shared__ __align__(16) __hip_bfloat16 hs[60 * 72];   // h halo 6x10 [pix][c],      8.6 KB
    __shared__ __align__(16) float lg[32 * 114];           // logits [pix][n],          14.6 KB
    __shared__ __align__(16) float ks[100 * 33];           // ker [t*4+g][pix],         13.2 KB

    int b    = blockIdx.x >> 7;
    int tile = blockIdx.x & 127;
    int ty0 = (tile >> 3) * 4;
    int tx0 = (tile & 7) * 8;
    int tid = threadIdx.x;
    int lane = tid & 63, wave = tid >> 6;
    int q = lane >> 4, m = lane & 15;

    // ---- preload phase-B B-frags (w1) + BN pair ----
    int bnt = wave >> 2;                      // phase-B N-tile 0..3
    int bo  = bnt * 16 + m;                   // phase-B output channel
    const __hip_bfloat16* w1b = (const __hip_bfloat16*)(ws + OFF_W1B);
    short8 bw[4];
    #pragma unroll
    for (int s = 0; s < 4; ++s)
        bw[s] = *(const short8*)(w1b + bo * 128 + s * 32 + q * 8);
    float2 bnia = ((const float2*)(ws + OFF_BN))[bo];

    // ---- phase A: copy x 8x12 halo (bf16, pre-transposed) -> xs, b128 in/out ----
    const __hip_bfloat16* xg = (const __hip_bfloat16*)(ws + OFF_XG) + (size_t)b * 16 * 4096 * 8;
    #pragma unroll
    for (int it = 0; it < 2; ++it) {
        int idx = tid + it * 1024;            // 1536 = 16 cq * 96 pix
        if (idx < 1536) {
            int cq = idx / 96, p = idx - cq * 96;
            int hy = p / 12, hx = p - hy * 12;
            int gy = ty0 + hy - 2, gx = tx0 + hx - 2;
            short8 v;
            #pragma unroll
            for (int j = 0; j < 8; ++j) v[j] = 0;
            if ((unsigned)gy < 64u && (unsigned)gx < 64u)
                v = *(const short8*)(xg + ((size_t)cq * 4096 + gy * 64 + gx) * 8);
            *(short8*)(&xs[idx * 8]) = v;
        }
    }
    __syncthreads();

    // ---- phase B: h = relu(bn(w1 @ x)) via MFMA: M=60 halo pix, N=64, K=128 ----
    {
        int mt = wave & 3;                    // 4 M-tiles x 4 N-tiles
        int hp = mt * 16 + m;                 // halo pixel (rows 60..63 garbage, masked)
        int hy1 = hp / 10, hx1 = hp - hy1 * 10;
        int xrow = (hy1 + 1) * 12 + (hx1 + 1);
        floatx4 acc;
        #pragma unroll
        for (int r = 0; r < 4; ++r) acc[r] = 0.f;
        #pragma unroll
        for (int s = 0; s < 4; ++s) {
            short8 a = *(const short8*)(&xs[((s * 4 + q) * 96 + xrow) * 8]);
            acc = __builtin_amdgcn_mfma_f32_16x16x32_bf16(a, bw[s], acc, 0, 0, 0);
        }
        #pragma unroll
        for (int r = 0; r < 4; ++r) {
            int prow = mt * 16 + q * 4 + r;
            if (prow < 60) {
                int phy = prow / 10, phx = prow - phy * 10;
                int gy = ty0 + phy - 1, gx = tx0 + phx - 1;
                bool in = ((unsigned)gy < 64u) && ((unsigned)gx < 64u);
                float v = in ? fmaxf(fmaf(acc[r], bnia.x, bnia.y), 0.f) : 0.f;
                hs[prow * 72 + bo] = __float2bfloat16(v);
            }
        }
    }
    __syncthreads();

    // ---- phase C: 3x3 conv via MFMA: M=32 pix, N=112, K=576 ----
    {
        int mt = wave & 1, nt = wave >> 1;    // 2 M-tiles x 8 N-slots (nt=7 idle)
        if (nt < 7) {
            int pixidx = mt * 16 + m;
            int py = pixidx >> 3, px = pixidx & 7;
            const __hip_bfloat16* w2b = (const __hip_bfloat16*)(ws + OFF_W2B);
            const __hip_bfloat16* bp  = w2b + (size_t)(nt * 16 + m) * 576 + q * 8;

            floatx4 acc;
            #pragma unroll
            for (int r = 0; r < 4; ++r) acc[r] = 0.f;

            short8 bcur = *(const short8*)bp;
            for (int s = 0; s < 18; ++s) {
                int t = s >> 1, c0 = (s & 1) * 32;
                int ti = t / 3, tj = t - ti * 3;
                short8 a = *(const short8*)(&hs[((py + ti) * 10 + px + tj) * 72 + c0 + q * 8]);
                short8 bn2 = bcur;
                if (s < 17) bn2 = *(const short8*)(bp + (s + 1) * 32);
                acc = __builtin_amdgcn_mfma_f32_16x16x32_bf16(a, bcur, acc, 0, 0, 0);
                bcur = bn2;
            }
            #pragma unroll
            for (int r = 0; r < 4; ++r)
                lg[(mt * 16 + q * 4 + r) * 114 + nt * 16 + m] = acc[r];
        }
    }
    __syncthreads();

    // ---- phase D: softmax over 25 taps -> ks [t*4+g][pix] ----
    if (tid < 128) {
        int pix = tid & 31, g = tid >> 5;
        float v[25];
        #pragma unroll
        for (int wi = 0; wi < 25; ++wi) v[wi] = lg[pix * 114 + g * 25 + wi];
        float mx = v[0];
        #pragma unroll
        for (int wi = 1; wi < 25; ++wi) mx = fmaxf(mx, v[wi]);
        float ssum = 0.f;
        #pragma unroll
        for (int wi = 0; wi < 25; ++wi) { v[wi] = __expf(v[wi] - mx); ssum += v[wi]; }
        float rs = 1.f / ssum;
        #pragma unroll
        for (int t25 = 0; t25 < 25; ++t25)
            ks[(t25 * 4 + g) * 33 + pix] = v[t25] * rs;
    }
    __syncthreads();

    // ---- phase E: 5x5 reassembly + pixel shuffle ----
    // thread = (pix 0..31, chunk = g-pair); ch-oct = wave; 8 ch x 2 g per thread
    {
        int pix   = lane & 31;
        int chunk = lane >> 5;                // 0 -> g{0,1} (row 2Y), 1 -> g{2,3} (row 2Y+1)
        int co    = wave;                     // ch-oct 0..15
        int py = pix >> 3, px = pix & 7;
        int Y = ty0 + py, X = tx0 + px;

        float acc[16];  // [8 ch][2 g]
        #pragma unroll
        for (int i = 0; i < 16; ++i) acc[i] = 0.f;

        const __hip_bfloat16* xsb = xs + (size_t)co * 96 * 8;
        #pragma unroll 5
        for (int t = 0; t < 25; ++t) {
            int ti = t / 5, tj = t - ti * 5;
            int xrow = (py + ti) * 12 + (px + tj);
            union { short8 s; unsigned u[4]; } xv;
            xv.s = *(const short8*)(xsb + xrow * 8);           // broadcast across chunk pair
            float k0 = ks[(t * 4 + chunk * 2 + 0) * 33 + pix]; // conflict-free stride-1
            float k1 = ks[(t * 4 + chunk * 2 + 1) * 33 + pix];
            #pragma unroll
            for (int j = 0; j < 4; ++j) {
                float xa = bfbits(xv.u[j] << 16);
                float xb2 = bfbits(xv.u[j] & 0xFFFF0000u);
                acc[(j * 2 + 0) * 2 + 0] = fmaf(xa,  k0, acc[(j * 2 + 0) * 2 + 0]);
                acc[(j * 2 + 0) * 2 + 1] = fmaf(xa,  k1, acc[(j * 2 + 0) * 2 + 1]);
                acc[(j * 2 + 1) * 2 + 0] = fmaf(xb2, k0, acc[(j * 2 + 1) * 2 + 0]);
                acc[(j * 2 + 1) * 2 + 1] = fmaf(xb2, k1, acc[(j * 2 + 1) * 2 + 1]);
            }
        }

        #pragma unroll
        for (int i = 0; i < 8; ++i) {
            size_t o0 = (((size_t)b * 128 + co * 8 + i) * 128 + 2 * Y + chunk) * 128 + 2 * X;
            *(float2*)(out + o0) = make_float2(acc[i * 2 + 0], acc[i * 2 + 1]);
        }
    }
}

extern "C" void kernel_launch(void* const* d_in, const int* in_sizes, int n_in,
                              void* d_out, int out_size, void* d_ws, size_t ws_size,
                              hipStream_t stream) {
    const float* x     = (const float*)d_in[0];
    const float* w1    = (const float*)d_in[1];
    const float* w2    = (const float*)d_in[2];
    const float* gamma = (const float*)d_in[3];
    const float* beta  = (const float*)d_in[4];
    const float* mean  = (const float*)d_in[5];
    const float* var   = (const float*)d_in[6];
    float* out = (float*)d_out;
    char*  ws  = (char*)d_ws;

    prep_kernel<<<1309, 256, 0, stream>>>(x, w1, w2, gamma, beta, mean, var, ws);
    fused_carafe<<<512, 1024, 0, stream>>>(ws, out);
}